// Round 8
// baseline (373.500 us; speedup 1.0000x reference)
//
#include <hip/hip_runtime.h>
#include <cstdint>

#define DIM 128
#define NCEN 8

typedef __attribute__((ext_vector_type(8))) short short8;   // 8 bf16
typedef _Float16 half8 __attribute__((ext_vector_type(8))); // 8 fp16
typedef __attribute__((ext_vector_type(4))) float f32x4;

constexpr float TAU   = 1e-5f;    // margin threshold for exact-recompute
constexpr float SCL   = 4096.0f;  // 2^12 pre-scale (dodge fp16 subnormals)
constexpr float UNSCL = 1.0f / (SCL * SCL);  // 2^-24, exact
constexpr int ROW_BYTES = 512;    // row slot: z bf16 in [0,256), vn @256

__device__ __forceinline__ unsigned bf16rne(float f) {
    unsigned u = __float_as_uint(f);
    return (u + 0x7FFFu + ((u >> 16) & 1u)) >> 16;
}

// ===== Phase 1: norm -> rotate (split-fp16 MFMA, operand-swapped) -> quantize -> z =====
constexpr int P1_BLOCK = 512;
constexpr int P1_TILES = 2;                    // 16-row tiles per wave
constexpr int P1_RPB   = 8 * 16 * P1_TILES;    // 256 rows/block -> grid 512

__global__ __launch_bounds__(P1_BLOCK, 4)      // 4 waves/EU -> VGPR<=128, 2 blocks/CU
void k_rotquant(const float* __restrict__ x, const float* __restrict__ Pi,
                const float* __restrict__ cen, char* __restrict__ zout)
{
    // Pi*4096 as fp16 hi/lo, row-major [d][k], 16B chunks XOR-swizzled by d&7
    __shared__ _Float16 bh[DIM * DIM];   // 32 KB
    __shared__ _Float16 bl[DIM * DIM];   // 32 KB

    const int tid  = threadIdx.x;
    const int wave = tid >> 6;
    const int lane = tid & 63;
    const int m = lane & 15, q = lane >> 4;

    // ---- stage split Pi (round-7 proven) ----
    {
        const int d  = tid >> 2;
        const int qt = tid & 3;
        const float* pr = Pi + (size_t)d * DIM + qt * 32;
        const int swz = d & 7;
#pragma unroll
        for (int c = 0; c < 4; ++c) {
            float4 v0 = *reinterpret_cast<const float4*>(pr + c * 8);
            float4 v1 = *reinterpret_cast<const float4*>(pr + c * 8 + 4);
            float vv[8] = {v0.x, v0.y, v0.z, v0.w, v1.x, v1.y, v1.z, v1.w};
            half8 hv, lv;
#pragma unroll
            for (int j = 0; j < 8; ++j) {
                float s = vv[j] * SCL;
                _Float16 h = (_Float16)s;
                hv[j] = h;
                lv[j] = (_Float16)(s - (float)h);
            }
            const int off = d * DIM + ((qt * 4 + c) ^ swz) * 8;
            *reinterpret_cast<half8*>(bh + off) = hv;
            *reinterpret_cast<half8*>(bl + off) = lv;
        }
    }
    __syncthreads();

    float cv[NCEN], mmid[NCEN - 1];
#pragma unroll
    for (int i = 0; i < NCEN; ++i) cv[i] = cen[i];
#pragma unroll
    for (int i = 0; i < NCEN - 1; ++i) mmid[i] = 0.5f * (cv[i] + cv[i + 1]);

    // prologue: tile 0 x load (B-frag layout: row m, k = kf*32 + q*8 + j)
    float xv[4][8];
    {
        const int rb0 = blockIdx.x * P1_RPB + wave * P1_TILES * 16;
        const float* xp = x + (size_t)(rb0 + m) * DIM + q * 8;
#pragma unroll
        for (int kf = 0; kf < 4; ++kf) {
            *reinterpret_cast<float4*>(&xv[kf][0]) = *reinterpret_cast<const float4*>(xp + kf * 32);
            *reinterpret_cast<float4*>(&xv[kf][4]) = *reinterpret_cast<const float4*>(xp + kf * 32 + 4);
        }
    }

    for (int t = 0; t < P1_TILES; ++t) {
        const int rowbase = blockIdx.x * P1_RPB + (wave * P1_TILES + t) * 16;
        const size_t rowoff = (size_t)(rowbase + m) * ROW_BYTES;

        // ---- fast norm (order-free; flagged coords redo numpy-order exactly) ----
        float s = 0.f;
#pragma unroll
        for (int kf = 0; kf < 4; ++kf)
#pragma unroll
            for (int j = 0; j < 8; ++j) s = fmaf(xv[kf][j], xv[kf][j], s);
        s += __shfl_xor(s, 16, 64);
        s += __shfl_xor(s, 32, 64);
        const float vn    = __fsqrt_rn(s);
        const float vne   = __fadd_rn(vn, 1e-8f);
        const float inv4k = __fdiv_rn(1.0f, vne) * SCL;
        if (q == 0) *reinterpret_cast<float*>(zout + rowoff + 256) = vn;

        // ---- fp16 split of scaled normalized x ----
        half8 xh[4], xl[4];
#pragma unroll
        for (int kf = 0; kf < 4; ++kf)
#pragma unroll
            for (int j = 0; j < 8; ++j) {
                float xs = xv[kf][j] * inv4k;
                _Float16 h = (_Float16)xs;
                xh[kf][j] = h;
                xl[kf][j] = (_Float16)(xs - (float)h);
            }

        // ---- prefetch next tile's x into xv (consumed next iteration) ----
        if (t + 1 < P1_TILES) {
            const float* xp = x + (size_t)(rowbase + 16 + m) * DIM + q * 8;
#pragma unroll
            for (int kf = 0; kf < 4; ++kf) {
                *reinterpret_cast<float4*>(&xv[kf][0]) = *reinterpret_cast<const float4*>(xp + kf * 32);
                *reinterpret_cast<float4*>(&xv[kf][4]) = *reinterpret_cast<const float4*>(xp + kf * 32 + 4);
            }
        }

        // ---- mm1 SWAPPED: D = Pi * xn^T. A = Pi (rows d), B = xn^T (cols = x-rows).
        //      Lane (m,q) ends with xr_scaled[row m][d = nt*16 + q*4 + qq]. ----
        f32x4 acc[8];
#pragma unroll
        for (int nt = 0; nt < 8; ++nt) {
            const int d1  = nt * 16 + m;
            const int ro  = d1 * DIM;
            const int swz = d1 & 7;
            f32x4 a = {0.f, 0.f, 0.f, 0.f};
#pragma unroll
            for (int kf = 0; kf < 4; ++kf) {
                const int off = ro + ((kf * 4 + q) ^ swz) * 8;
                half8 ph = *reinterpret_cast<const half8*>(bh + off);
                half8 pl = *reinterpret_cast<const half8*>(bl + off);
                a = __builtin_amdgcn_mfma_f32_16x16x32_f16(pl, xh[kf], a, 0, 0, 0);
                a = __builtin_amdgcn_mfma_f32_16x16x32_f16(ph, xl[kf], a, 0, 0, 0);
                a = __builtin_amdgcn_mfma_f32_16x16x32_f16(ph, xh[kf], a, 0, 0, 0);
            }
            acc[nt] = a;
        }

        // ---- quantize 32 coords (midpoint chain == first-min d2-argmin away
        //      from boundaries; margin-flagged) ; acc overwritten with qv ----
        unsigned sgb = 0u, flg = 0u;
        float as = 0.f;
#pragma unroll
        for (int nt = 0; nt < 8; ++nt)
#pragma unroll
            for (int qq = 0; qq < 4; ++qq) {
                const float xr = acc[nt][qq] * UNSCL;
                float t0   = __fsub_rn(xr, mmid[0]);
                float qv   = (t0 > 0.f) ? cv[1] : cv[0];
                float dmin = fabsf(t0);
#pragma unroll
                for (int i = 1; i < NCEN - 1; ++i) {
                    float ti = __fsub_rn(xr, mmid[i]);
                    qv   = (ti > 0.f) ? cv[i + 1] : qv;
                    dmin = fminf(dmin, fabsf(ti));
                }
                float res = __fsub_rn(xr, qv);
                float ar  = fabsf(res);
                dmin = fminf(dmin, ar);
                acc[nt][qq] = qv;
                const int b = nt * 4 + qq;
                if (res >= 0.f)  sgb |= 1u << b;
                if (dmin < TAU)  flg |= 1u << b;
                as += ar;
            }

        // ---- rare exact path: reproduce reference f32 pipeline for this coord ----
        if (flg) {
            const float* xrow = x + (size_t)(rowbase + m) * DIM;
            unsigned ff = flg;
            while (ff) {
                const int b = __builtin_ctz(ff);
                ff &= ff - 1;
                const int d = (b >> 2) * 16 + q * 4 + (b & 3);
                const float* prow = Pi + (size_t)d * DIM;
                // numpy-order norm
                float r8[8] = {0.f, 0.f, 0.f, 0.f, 0.f, 0.f, 0.f, 0.f};
                for (int c8 = 0; c8 < 8; ++c8) {
                    float xc[16];
#pragma unroll
                    for (int i = 0; i < 4; ++i)
                        *reinterpret_cast<float4*>(&xc[4 * i]) =
                            *reinterpret_cast<const float4*>(xrow + c8 * 16 + 4 * i);
#pragma unroll
                    for (int tl = 0; tl < 2; ++tl)
#pragma unroll
                        for (int jj = 0; jj < 8; ++jj)
                            r8[jj] = fmaf(xc[tl * 8 + jj], xc[tl * 8 + jj], r8[jj]);
                }
                float rr = __fadd_rn(
                    __fadd_rn(__fadd_rn(r8[0], r8[1]), __fadd_rn(r8[2], r8[3])),
                    __fadd_rn(__fadd_rn(r8[4], r8[5]), __fadd_rn(r8[6], r8[7])));
                const float vneX = __fadd_rn(__fsqrt_rn(rr), 1e-8f);
                // exact ascending-k f32 chain
                float accX = 0.f;
                for (int c8 = 0; c8 < 8; ++c8) {
                    float xc[16], pc[16];
#pragma unroll
                    for (int i = 0; i < 4; ++i) {
                        *reinterpret_cast<float4*>(&xc[4 * i]) =
                            *reinterpret_cast<const float4*>(xrow + c8 * 16 + 4 * i);
                        *reinterpret_cast<float4*>(&pc[4 * i]) =
                            *reinterpret_cast<const float4*>(prow + c8 * 16 + 4 * i);
                    }
#pragma unroll
                    for (int kk = 0; kk < 16; ++kk)
                        accX = fmaf(__fdiv_rn(xc[kk], vneX), pc[kk], accX);
                }
                // exact f32 d2-argmin, first-min tie-break
                float dd   = __fsub_rn(accX, cv[0]);
                float best = __fmul_rn(dd, dd);
                float qe   = cv[0];
#pragma unroll
                for (int i = 1; i < NCEN; ++i) {
                    float di = __fsub_rn(accX, cv[i]);
                    float d2 = __fmul_rn(di, di);
                    bool  c  = d2 < best;
                    best = c ? d2 : best;
                    qe   = c ? cv[i] : qe;
                }
                const float rese = __fsub_rn(accX, qe);
                // static-index fixup (rold approx via accX: smooth, err ~1e-7)
#pragma unroll
                for (int s32 = 0; s32 < 32; ++s32)
                    if (s32 == b) {
                        as = as - fabsf(accX - acc[s32 >> 2][s32 & 3]) + fabsf(rese);
                        acc[s32 >> 2][s32 & 3] = qe;
                    }
                sgb = (rese >= 0.f) ? (sgb | (1u << b)) : (sgb & ~(1u << b));
            }
        }

        // ---- residual scale (q-reduce covers row m's 128 coords) + z store ----
        as += __shfl_xor(as, 16, 64);
        as += __shfl_xor(as, 32, 64);
        const float sc = as * (1.0f / 128.0f);
#pragma unroll
        for (int nt = 0; nt < 8; ++nt) {
            float z0 = __fadd_rn(acc[nt][0], ((sgb >> (nt * 4 + 0)) & 1u) ? sc : -sc);
            float z1 = __fadd_rn(acc[nt][1], ((sgb >> (nt * 4 + 1)) & 1u) ? sc : -sc);
            float z2 = __fadd_rn(acc[nt][2], ((sgb >> (nt * 4 + 2)) & 1u) ? sc : -sc);
            float z3 = __fadd_rn(acc[nt][3], ((sgb >> (nt * 4 + 3)) & 1u) ? sc : -sc);
            uint2 pz = make_uint2(bf16rne(z0) | (bf16rne(z1) << 16),
                                  bf16rne(z2) | (bf16rne(z3) << 16));
            *reinterpret_cast<uint2*>(zout + rowoff + nt * 32 + q * 8) = pz;
        }
    }
}

// ===== Phase 2: out = (z @ Pi) * vn via bf16 MFMA — round-5 proven, verbatim =====
constexpr int BBLOCK = 256;
constexpr int BROWS  = 256;

__global__ __launch_bounds__(BBLOCK, 8)
void pq_phase2(const float* __restrict__ Pi, char* __restrict__ zio)
{
    __shared__ unsigned short piT[DIM * DIM];   // 32 KB

    const int tid  = threadIdx.x;
    const int wave = tid >> 6;
    const int lane = tid & 63;

#pragma unroll
    for (int s = 0; s < 4; ++s) {
        int sub = tid + s * BBLOCK;
        int a4 = (sub & 31) * 4;
        int b4 = (sub >> 5) * 4;
        float rv[4][4];
#pragma unroll
        for (int i = 0; i < 4; ++i)
            *reinterpret_cast<float4*>(rv[i]) =
                *reinterpret_cast<const float4*>(Pi + (size_t)(a4 + i) * DIM + b4);
#pragma unroll
        for (int j = 0; j < 4; ++j) {
            const int n   = b4 + j;
            const int ksw = a4 ^ ((n & 7) << 3);
            unsigned lo = bf16rne(rv[0][j]) | (bf16rne(rv[1][j]) << 16);
            unsigned hi = bf16rne(rv[2][j]) | (bf16rne(rv[3][j]) << 16);
            *reinterpret_cast<uint2*>(&piT[n * DIM + ksw]) = make_uint2(lo, hi);
        }
    }
    __syncthreads();

    const int rowbase0 = blockIdx.x * BROWS;

    for (int it = 0; it < BROWS / 64; ++it) {
        const int rowbase = rowbase0 + it * 64 + wave * 16;

        const char* zr = zio + (size_t)(rowbase + (lane & 15)) * ROW_BYTES + ((lane >> 4) * 16);
        short8 afr[4];
#pragma unroll
        for (int kf = 0; kf < 4; ++kf)
            afr[kf] = *reinterpret_cast<const short8*>(zr + kf * 64);

        float vnr[4];
#pragma unroll
        for (int qq = 0; qq < 4; ++qq)
            vnr[qq] = *reinterpret_cast<const float*>(
                zio + (size_t)(rowbase + (lane >> 4) * 4 + qq) * ROW_BYTES + 256);

#pragma unroll
        for (int nt = 0; nt < 8; ++nt) {
            const int n = nt * 16 + (lane & 15);
            f32x4 acc = {0.f, 0.f, 0.f, 0.f};
#pragma unroll
            for (int kf = 0; kf < 4; ++kf) {
                const int k0  = kf * 32 + (lane >> 4) * 8;
                const int ksw = k0 ^ ((n & 7) << 3);
                short8 bfr = *reinterpret_cast<const short8*>(&piT[n * DIM + ksw]);
                acc = __builtin_amdgcn_mfma_f32_16x16x32_bf16(afr[kf], bfr, acc, 0, 0, 0);
            }
#pragma unroll
            for (int qq = 0; qq < 4; ++qq) {
                float o = __fmul_rn(acc[qq], vnr[qq]);
                *reinterpret_cast<float*>(
                    zio + (size_t)(rowbase + (lane >> 4) * 4 + qq) * ROW_BYTES
                        + (size_t)(nt * 16 + (lane & 15)) * 4) = o;
            }
        }
    }
}

extern "C" void kernel_launch(void* const* d_in, const int* in_sizes, int n_in,
                              void* d_out, int out_size, void* d_ws, size_t ws_size,
                              hipStream_t stream) {
    const float* x   = (const float*)d_in[0];
    const float* Pi  = (const float*)d_in[1];
    const float* cen = (const float*)d_in[2];
    char* outp       = (char*)d_out;

    const int n_rows = in_sizes[0] / DIM;

    hipLaunchKernelGGL(k_rotquant, dim3(n_rows / P1_RPB), dim3(P1_BLOCK), 0, stream,
                       x, Pi, cen, outp);
    hipLaunchKernelGGL(pq_phase2, dim3(n_rows / BROWS), dim3(BBLOCK), 0, stream,
                       Pi, outp);
}

// Round 9
// 351.706 us; speedup vs baseline: 1.0620x; 1.0620x over previous
//
#include <hip/hip_runtime.h>
#include <cstdint>

#define DIM 128
#define NCEN 8

typedef __attribute__((ext_vector_type(8))) short short8;   // 8 bf16
typedef _Float16 half8 __attribute__((ext_vector_type(8))); // 8 fp16
typedef __attribute__((ext_vector_type(4))) float f32x4;

constexpr float TAU   = 1e-5f;    // margin threshold for exact-recompute
constexpr float SCL   = 4096.0f;  // 2^12 pre-scale (dodge fp16 subnormals)
constexpr float UNSCL = 1.0f / (SCL * SCL);  // 2^-24, exact
constexpr int ROW_BYTES = 512;    // row slot: z bf16 in [0,256), vn @256

__device__ __forceinline__ unsigned bf16rne(float f) {
    unsigned u = __float_as_uint(f);
    return (u + 0x7FFFu + ((u >> 16) & 1u)) >> 16;
}

// ---- cold path: reproduce the reference f32 pipeline for ONE coordinate ----
// (numpy pairwise norm, IEEE divides, ascending-k fmaf chain, first-min d2 argmin)
__device__ __attribute__((noinline))
float2 exact_coord(const float* __restrict__ xrow, const float* __restrict__ prow,
                   const float* __restrict__ cen)
{
    float r8[8] = {0.f, 0.f, 0.f, 0.f, 0.f, 0.f, 0.f, 0.f};
    for (int c8 = 0; c8 < 8; ++c8) {
        float xc[16];
#pragma unroll
        for (int i = 0; i < 4; ++i)
            *reinterpret_cast<float4*>(&xc[4 * i]) =
                *reinterpret_cast<const float4*>(xrow + c8 * 16 + 4 * i);
#pragma unroll
        for (int tl = 0; tl < 2; ++tl)
#pragma unroll
            for (int jj = 0; jj < 8; ++jj)
                r8[jj] = fmaf(xc[tl * 8 + jj], xc[tl * 8 + jj], r8[jj]);
    }
    float rr = __fadd_rn(
        __fadd_rn(__fadd_rn(r8[0], r8[1]), __fadd_rn(r8[2], r8[3])),
        __fadd_rn(__fadd_rn(r8[4], r8[5]), __fadd_rn(r8[6], r8[7])));
    const float vneX = __fadd_rn(__fsqrt_rn(rr), 1e-8f);
    float accX = 0.f;
    for (int c8 = 0; c8 < 8; ++c8) {
        float xc[16], pc[16];
#pragma unroll
        for (int i = 0; i < 4; ++i) {
            *reinterpret_cast<float4*>(&xc[4 * i]) =
                *reinterpret_cast<const float4*>(xrow + c8 * 16 + 4 * i);
            *reinterpret_cast<float4*>(&pc[4 * i]) =
                *reinterpret_cast<const float4*>(prow + c8 * 16 + 4 * i);
        }
#pragma unroll
        for (int kk = 0; kk < 16; ++kk)
            accX = fmaf(__fdiv_rn(xc[kk], vneX), pc[kk], accX);
    }
    float c0 = cen[0];
    float dd   = __fsub_rn(accX, c0);
    float best = __fmul_rn(dd, dd);
    float qe   = c0;
#pragma unroll
    for (int i = 1; i < NCEN; ++i) {
        float ci = cen[i];
        float di = __fsub_rn(accX, ci);
        float d2 = __fmul_rn(di, di);
        bool  c  = d2 < best;
        best = c ? d2 : best;
        qe   = c ? ci : qe;
    }
    return make_float2(qe, __fsub_rn(accX, qe));
}

// ===== Phase 1: norm -> rotate (split-fp16 MFMA, swapped) -> quantize -> z =====
constexpr int P1_BLOCK = 512;
constexpr int P1_TILES = 2;                    // 16-row tiles per wave
constexpr int P1_RPB   = 8 * 16 * P1_TILES;    // 256 rows/block

__global__ __launch_bounds__(P1_BLOCK, 4)      // VGPR cap 128, 2 blocks/CU
void k_rotquant(const float* __restrict__ x, const float* __restrict__ Pi,
                const float* __restrict__ cen, char* __restrict__ zout)
{
    __shared__ _Float16 bh[DIM * DIM];   // 32 KB  (Pi*4096 hi)
    __shared__ _Float16 bl[DIM * DIM];   // 32 KB  (Pi*4096 lo)

    const int tid  = threadIdx.x;
    const int wave = tid >> 6;
    const int lane = tid & 63;
    const int m = lane & 15, q = lane >> 4;

    // ---- stage split Pi (round-7/8 proven) ----
    {
        const int d  = tid >> 2;
        const int qt = tid & 3;
        const float* pr = Pi + (size_t)d * DIM + qt * 32;
        const int swz = d & 7;
#pragma unroll
        for (int c = 0; c < 4; ++c) {
            float4 v0 = *reinterpret_cast<const float4*>(pr + c * 8);
            float4 v1 = *reinterpret_cast<const float4*>(pr + c * 8 + 4);
            float vv[8] = {v0.x, v0.y, v0.z, v0.w, v1.x, v1.y, v1.z, v1.w};
            half8 hv, lv;
#pragma unroll
            for (int j = 0; j < 8; ++j) {
                float s = vv[j] * SCL;
                _Float16 h = (_Float16)s;
                hv[j] = h;
                lv[j] = (_Float16)(s - (float)h);
            }
            const int off = d * DIM + ((qt * 4 + c) ^ swz) * 8;
            *reinterpret_cast<half8*>(bh + off) = hv;
            *reinterpret_cast<half8*>(bl + off) = lv;
        }
    }
    __syncthreads();

    float cv[NCEN], mmid[NCEN - 1];
#pragma unroll
    for (int i = 0; i < NCEN; ++i) cv[i] = cen[i];
#pragma unroll
    for (int i = 0; i < NCEN - 1; ++i) mmid[i] = 0.5f * (cv[i] + cv[i + 1]);

    for (int t = 0; t < P1_TILES; ++t) {
        const int rowbase = blockIdx.x * P1_RPB + (wave * P1_TILES + t) * 16;
        const size_t rowoff = (size_t)(rowbase + m) * ROW_BYTES;

        // ---- load x (B-frag layout: row m, k = kf*32 + q*8 + j) ----
        half8 xh[4], xl[4];
        {
            const float* xp = x + (size_t)(rowbase + m) * DIM + q * 8;
            float xv[4][8];
#pragma unroll
            for (int kf = 0; kf < 4; ++kf) {
                *reinterpret_cast<float4*>(&xv[kf][0]) =
                    *reinterpret_cast<const float4*>(xp + kf * 32);
                *reinterpret_cast<float4*>(&xv[kf][4]) =
                    *reinterpret_cast<const float4*>(xp + kf * 32 + 4);
            }
            // fast norm (order-free; flagged coords redo numpy-order exactly)
            float s = 0.f;
#pragma unroll
            for (int kf = 0; kf < 4; ++kf)
#pragma unroll
                for (int j = 0; j < 8; ++j) s = fmaf(xv[kf][j], xv[kf][j], s);
            s += __shfl_xor(s, 16, 64);
            s += __shfl_xor(s, 32, 64);
            const float vn    = __fsqrt_rn(s);
            const float inv4k = __fdiv_rn(1.0f, __fadd_rn(vn, 1e-8f)) * SCL;
            if (q == 0) *reinterpret_cast<float*>(zout + rowoff + 256) = vn;
            // fp16 split of scaled normalized x; xv dies here
#pragma unroll
            for (int kf = 0; kf < 4; ++kf)
#pragma unroll
                for (int j = 0; j < 8; ++j) {
                    float xs = xv[kf][j] * inv4k;
                    _Float16 h = (_Float16)xs;
                    xh[kf][j] = h;
                    xl[kf][j] = (_Float16)(xs - (float)h);
                }
        }

        // ---- per-nt: MFMA then immediate quantize (acc dies per nt) ----
        float qv[8][4];                 // all-static indexing -> registers
        unsigned sgb = 0u;
        float as = 0.f;
#pragma unroll
        for (int nt = 0; nt < 8; ++nt) {
            const int d1  = nt * 16 + m;
            const int ro  = d1 * DIM;
            const int swz = d1 & 7;
            f32x4 a = {0.f, 0.f, 0.f, 0.f};
#pragma unroll
            for (int kf = 0; kf < 4; ++kf) {
                const int off = ro + ((kf * 4 + q) ^ swz) * 8;
                half8 ph = *reinterpret_cast<const half8*>(bh + off);
                half8 pl = *reinterpret_cast<const half8*>(bl + off);
                a = __builtin_amdgcn_mfma_f32_16x16x32_f16(pl, xh[kf], a, 0, 0, 0);
                a = __builtin_amdgcn_mfma_f32_16x16x32_f16(ph, xl[kf], a, 0, 0, 0);
                a = __builtin_amdgcn_mfma_f32_16x16x32_f16(ph, xh[kf], a, 0, 0, 0);
            }
#pragma unroll
            for (int qq = 0; qq < 4; ++qq) {
                const float xr = a[qq] * UNSCL;
                float t0   = __fsub_rn(xr, mmid[0]);
                float qf   = (t0 > 0.f) ? cv[1] : cv[0];
                float dmin = fabsf(t0);
#pragma unroll
                for (int i = 1; i < NCEN - 1; ++i) {
                    float ti = __fsub_rn(xr, mmid[i]);
                    qf   = (ti > 0.f) ? cv[i + 1] : qf;
                    dmin = fminf(dmin, fabsf(ti));
                }
                float res = __fsub_rn(xr, qf);
                float ar  = fabsf(res);
                dmin = fminf(dmin, ar);
                if (dmin < TAU) {   // rare: decide this coord exactly
                    const int dco = nt * 16 + q * 4 + qq;
                    float2 er = exact_coord(x + (size_t)(rowbase + m) * DIM,
                                            Pi + (size_t)dco * DIM, cen);
                    qf  = er.x;
                    res = er.y;
                    ar  = fabsf(res);
                }
                qv[nt][qq] = qf;
                if (res >= 0.f) sgb |= 1u << (nt * 4 + qq);
                as += ar;
            }
        }

        // ---- residual scale (q-reduce: row m's 128 coords) + z store ----
        as += __shfl_xor(as, 16, 64);
        as += __shfl_xor(as, 32, 64);
        const float sc = as * (1.0f / 128.0f);
#pragma unroll
        for (int nt = 0; nt < 8; ++nt) {
            float z0 = __fadd_rn(qv[nt][0], ((sgb >> (nt * 4 + 0)) & 1u) ? sc : -sc);
            float z1 = __fadd_rn(qv[nt][1], ((sgb >> (nt * 4 + 1)) & 1u) ? sc : -sc);
            float z2 = __fadd_rn(qv[nt][2], ((sgb >> (nt * 4 + 2)) & 1u) ? sc : -sc);
            float z3 = __fadd_rn(qv[nt][3], ((sgb >> (nt * 4 + 3)) & 1u) ? sc : -sc);
            uint2 pz = make_uint2(bf16rne(z0) | (bf16rne(z1) << 16),
                                  bf16rne(z2) | (bf16rne(z3) << 16));
            *reinterpret_cast<uint2*>(zout + rowoff + nt * 32 + q * 8) = pz;
        }
    }
}

// ===== Phase 2: out = (z @ Pi) * vn via bf16 MFMA — round-5 proven, verbatim =====
constexpr int BBLOCK = 256;
constexpr int BROWS  = 256;

__global__ __launch_bounds__(BBLOCK, 8)
void pq_phase2(const float* __restrict__ Pi, char* __restrict__ zio)
{
    __shared__ unsigned short piT[DIM * DIM];   // 32 KB

    const int tid  = threadIdx.x;
    const int wave = tid >> 6;
    const int lane = tid & 63;

#pragma unroll
    for (int s = 0; s < 4; ++s) {
        int sub = tid + s * BBLOCK;
        int a4 = (sub & 31) * 4;
        int b4 = (sub >> 5) * 4;
        float rv[4][4];
#pragma unroll
        for (int i = 0; i < 4; ++i)
            *reinterpret_cast<float4*>(rv[i]) =
                *reinterpret_cast<const float4*>(Pi + (size_t)(a4 + i) * DIM + b4);
#pragma unroll
        for (int j = 0; j < 4; ++j) {
            const int n   = b4 + j;
            const int ksw = a4 ^ ((n & 7) << 3);
            unsigned lo = bf16rne(rv[0][j]) | (bf16rne(rv[1][j]) << 16);
            unsigned hi = bf16rne(rv[2][j]) | (bf16rne(rv[3][j]) << 16);
            *reinterpret_cast<uint2*>(&piT[n * DIM + ksw]) = make_uint2(lo, hi);
        }
    }
    __syncthreads();

    const int rowbase0 = blockIdx.x * BROWS;

    for (int it = 0; it < BROWS / 64; ++it) {
        const int rowbase = rowbase0 + it * 64 + wave * 16;

        const char* zr = zio + (size_t)(rowbase + (lane & 15)) * ROW_BYTES + ((lane >> 4) * 16);
        short8 afr[4];
#pragma unroll
        for (int kf = 0; kf < 4; ++kf)
            afr[kf] = *reinterpret_cast<const short8*>(zr + kf * 64);

        float vnr[4];
#pragma unroll
        for (int qq = 0; qq < 4; ++qq)
            vnr[qq] = *reinterpret_cast<const float*>(
                zio + (size_t)(rowbase + (lane >> 4) * 4 + qq) * ROW_BYTES + 256);

#pragma unroll
        for (int nt = 0; nt < 8; ++nt) {
            const int n = nt * 16 + (lane & 15);
            f32x4 acc = {0.f, 0.f, 0.f, 0.f};
#pragma unroll
            for (int kf = 0; kf < 4; ++kf) {
                const int k0  = kf * 32 + (lane >> 4) * 8;
                const int ksw = k0 ^ ((n & 7) << 3);
                short8 bfr = *reinterpret_cast<const short8*>(&piT[n * DIM + ksw]);
                acc = __builtin_amdgcn_mfma_f32_16x16x32_bf16(afr[kf], bfr, acc, 0, 0, 0);
            }
#pragma unroll
            for (int qq = 0; qq < 4; ++qq) {
                float o = __fmul_rn(acc[qq], vnr[qq]);
                *reinterpret_cast<float*>(
                    zio + (size_t)(rowbase + (lane >> 4) * 4 + qq) * ROW_BYTES
                        + (size_t)(nt * 16 + (lane & 15)) * 4) = o;
            }
        }
    }
}

extern "C" void kernel_launch(void* const* d_in, const int* in_sizes, int n_in,
                              void* d_out, int out_size, void* d_ws, size_t ws_size,
                              hipStream_t stream) {
    const float* x   = (const float*)d_in[0];
    const float* Pi  = (const float*)d_in[1];
    const float* cen = (const float*)d_in[2];
    char* outp       = (char*)d_out;

    const int n_rows = in_sizes[0] / DIM;

    hipLaunchKernelGGL(k_rotquant, dim3(n_rows / P1_RPB), dim3(P1_BLOCK), 0, stream,
                       x, Pi, cen, outp);
    hipLaunchKernelGGL(pq_phase2, dim3(n_rows / BROWS), dim3(BBLOCK), 0, stream,
                       Pi, outp);
}

// Round 10
// 236.453 us; speedup vs baseline: 1.5796x; 1.4874x over previous
//
#include <hip/hip_runtime.h>
#include <cstdint>

#define DIM 128
#define NCEN 8

typedef __attribute__((ext_vector_type(8))) short short8;   // 8 bf16
typedef _Float16 half8 __attribute__((ext_vector_type(8))); // 8 fp16
typedef __attribute__((ext_vector_type(4))) float f32x4;

constexpr float TAU   = 1e-5f;    // margin threshold for exact-recompute
constexpr float SCL   = 4096.0f;  // 2^12 pre-scale (dodge fp16 subnormals)
constexpr float UNSCL = 1.0f / (SCL * SCL);  // 2^-24, exact
constexpr int ROW_BYTES = 512;    // row slot: z bf16 in [0,256), vn @256

__device__ __forceinline__ unsigned bf16rne(float f) {
    unsigned u = __float_as_uint(f);
    return (u + 0x7FFFu + ((u >> 16) & 1u)) >> 16;
}

// ===== Phase 1: norm -> rotate (split-fp16 MFMA, swapped) -> quantize -> z =====
constexpr int P1_BLOCK = 512;
constexpr int P1_TILES = 2;                    // 16-row tiles per wave
constexpr int P1_RPB   = 8 * 16 * P1_TILES;    // 256 rows/block

__global__ __launch_bounds__(P1_BLOCK, 4)      // VGPR cap 128, 2 blocks/CU
void k_rotquant(const float* __restrict__ x, const float* __restrict__ Pi,
                const float* __restrict__ cen, char* __restrict__ zout)
{
    __shared__ _Float16 bh[DIM * DIM];   // 32 KB  (Pi*4096 hi)
    __shared__ _Float16 bl[DIM * DIM];   // 32 KB  (Pi*4096 lo)

    const int tid  = threadIdx.x;
    const int lane = tid & 63;
    const int m = lane & 15, q = lane >> 4;

    // ---- stage split Pi (proven) ----
    {
        const int d  = tid >> 2;
        const int qt = tid & 3;
        const float* pr = Pi + (size_t)d * DIM + qt * 32;
        const int swz = d & 7;
#pragma unroll
        for (int c = 0; c < 4; ++c) {
            float4 v0 = *reinterpret_cast<const float4*>(pr + c * 8);
            float4 v1 = *reinterpret_cast<const float4*>(pr + c * 8 + 4);
            float vv[8] = {v0.x, v0.y, v0.z, v0.w, v1.x, v1.y, v1.z, v1.w};
            half8 hv, lv;
#pragma unroll
            for (int j = 0; j < 8; ++j) {
                float s = vv[j] * SCL;
                _Float16 h = (_Float16)s;
                hv[j] = h;
                lv[j] = (_Float16)(s - (float)h);
            }
            const int off = d * DIM + ((qt * 4 + c) ^ swz) * 8;
            *reinterpret_cast<half8*>(bh + off) = hv;
            *reinterpret_cast<half8*>(bl + off) = lv;
        }
    }
    __syncthreads();

    float cv[NCEN], mmid[NCEN - 1];
#pragma unroll
    for (int i = 0; i < NCEN; ++i) cv[i] = cen[i];
#pragma unroll
    for (int i = 0; i < NCEN - 1; ++i) mmid[i] = 0.5f * (cv[i] + cv[i + 1]);

    for (int t = 0; t < P1_TILES; ++t) {
        const int rowbase = blockIdx.x * P1_RPB + ((tid >> 6) * P1_TILES + t) * 16;
        const size_t rowoff = (size_t)(rowbase + m) * ROW_BYTES;

        // ---- load x (B-frag layout: row m, k = kf*32 + q*8 + j) + split ----
        half8 xh[4], xl[4];
        {
            const float* xp = x + (size_t)(rowbase + m) * DIM + q * 8;
            float xv[4][8];
#pragma unroll
            for (int kf = 0; kf < 4; ++kf) {
                *reinterpret_cast<float4*>(&xv[kf][0]) =
                    *reinterpret_cast<const float4*>(xp + kf * 32);
                *reinterpret_cast<float4*>(&xv[kf][4]) =
                    *reinterpret_cast<const float4*>(xp + kf * 32 + 4);
            }
            float s = 0.f;
#pragma unroll
            for (int kf = 0; kf < 4; ++kf)
#pragma unroll
                for (int j = 0; j < 8; ++j) s = fmaf(xv[kf][j], xv[kf][j], s);
            s += __shfl_xor(s, 16, 64);
            s += __shfl_xor(s, 32, 64);
            const float vn    = __fsqrt_rn(s);
            const float inv4k = __fdiv_rn(1.0f, __fadd_rn(vn, 1e-8f)) * SCL;
            if (q == 0) *reinterpret_cast<float*>(zout + rowoff + 256) = vn;
#pragma unroll
            for (int kf = 0; kf < 4; ++kf)
#pragma unroll
                for (int j = 0; j < 8; ++j) {
                    float xs = xv[kf][j] * inv4k;
                    _Float16 h = (_Float16)xs;
                    xh[kf][j] = h;
                    xl[kf][j] = (_Float16)(xs - (float)h);
                }
        }

        // ---- per-nt MFMA + immediate quantize; state = packed nibbles ----
        uint32_t iw[4] = {0u, 0u, 0u, 0u};   // 3-bit centroid idx per coord (nibble)
        uint32_t sgb = 0u, flg = 0u;
        float as = 0.f;
#pragma unroll
        for (int nt = 0; nt < 8; ++nt) {
            const int d1  = nt * 16 + m;
            const int ro  = d1 * DIM;
            const int swz = d1 & 7;
            f32x4 a = {0.f, 0.f, 0.f, 0.f};
#pragma unroll
            for (int kf = 0; kf < 4; ++kf) {
                const int off = ro + ((kf * 4 + q) ^ swz) * 8;
                half8 ph = *reinterpret_cast<const half8*>(bh + off);
                half8 pl = *reinterpret_cast<const half8*>(bl + off);
                a = __builtin_amdgcn_mfma_f32_16x16x32_f16(pl, xh[kf], a, 0, 0, 0);
                a = __builtin_amdgcn_mfma_f32_16x16x32_f16(ph, xl[kf], a, 0, 0, 0);
                a = __builtin_amdgcn_mfma_f32_16x16x32_f16(ph, xh[kf], a, 0, 0, 0);
            }
#pragma unroll
            for (int qq = 0; qq < 4; ++qq) {
                const float xr = a[qq] * UNSCL;
                float t0   = __fsub_rn(xr, mmid[0]);
                float qf   = (t0 > 0.f) ? cv[1] : cv[0];
                int   qi   = (t0 > 0.f) ? 1 : 0;
                float dmin = fabsf(t0);
#pragma unroll
                for (int i = 1; i < NCEN - 1; ++i) {
                    float ti = __fsub_rn(xr, mmid[i]);
                    qf   = (ti > 0.f) ? cv[i + 1] : qf;
                    qi   = (ti > 0.f) ? i + 1 : qi;
                    dmin = fminf(dmin, fabsf(ti));
                }
                float res = __fsub_rn(xr, qf);
                float ar  = fabsf(res);
                dmin = fminf(dmin, ar);
                const int b = nt * 4 + qq;           // compile-time constant
                const bool bad = (dmin < TAU);
                iw[b >> 3] |= (uint32_t)qi << ((b & 7) * 4);   // static word/shift
                if (res >= 0.f) sgb |= 1u << b;
                if (bad)        flg |= 1u << b;
                as += bad ? 0.f : ar;                // flagged: contribute in fixup
            }
        }

        // ---- inline-once exact fixup (rare; xh/xl dead -> regs available).
        //      All state patches are bit ops / predicated selects: no scratch. ----
        while (flg) {
            const int b = (int)__builtin_ctz(flg);
            flg &= flg - 1u;
            const int dco = (b >> 2) * 16 + q * 4 + (b & 3);
            const float* xrow = x + (size_t)(rowbase + m) * DIM;
            const float* prow = Pi + (size_t)dco * DIM;
            // numpy pairwise norm
            float r8[8] = {0.f, 0.f, 0.f, 0.f, 0.f, 0.f, 0.f, 0.f};
            for (int c8 = 0; c8 < 8; ++c8) {
                float xc[16];
#pragma unroll
                for (int i = 0; i < 4; ++i)
                    *reinterpret_cast<float4*>(&xc[4 * i]) =
                        *reinterpret_cast<const float4*>(xrow + c8 * 16 + 4 * i);
#pragma unroll
                for (int tl = 0; tl < 2; ++tl)
#pragma unroll
                    for (int jj = 0; jj < 8; ++jj)
                        r8[jj] = fmaf(xc[tl * 8 + jj], xc[tl * 8 + jj], r8[jj]);
            }
            float rr = __fadd_rn(
                __fadd_rn(__fadd_rn(r8[0], r8[1]), __fadd_rn(r8[2], r8[3])),
                __fadd_rn(__fadd_rn(r8[4], r8[5]), __fadd_rn(r8[6], r8[7])));
            const float vneX = __fadd_rn(__fsqrt_rn(rr), 1e-8f);
            // exact ascending-k f32 chain
            float accX = 0.f;
            for (int c8 = 0; c8 < 8; ++c8) {
                float xc[16], pc[16];
#pragma unroll
                for (int i = 0; i < 4; ++i) {
                    *reinterpret_cast<float4*>(&xc[4 * i]) =
                        *reinterpret_cast<const float4*>(xrow + c8 * 16 + 4 * i);
                    *reinterpret_cast<float4*>(&pc[4 * i]) =
                        *reinterpret_cast<const float4*>(prow + c8 * 16 + 4 * i);
                }
#pragma unroll
                for (int kk = 0; kk < 16; ++kk)
                    accX = fmaf(__fdiv_rn(xc[kk], vneX), pc[kk], accX);
            }
            // exact f32 d2-argmin, first-min tie-break
            float dd   = __fsub_rn(accX, cv[0]);
            float best = __fmul_rn(dd, dd);
            int   qe   = 0;
#pragma unroll
            for (int i = 1; i < NCEN; ++i) {
                float di = __fsub_rn(accX, cv[i]);
                float d2 = __fmul_rn(di, di);
                bool  c  = d2 < best;
                best = c ? d2 : best;
                qe   = c ? i : qe;
            }
            float qev = cv[0];
#pragma unroll
            for (int i = 1; i < NCEN; ++i) qev = (qe == i) ? cv[i] : qev;
            const float rese = __fsub_rn(accX, qev);
            as += fabsf(rese);
            sgb = (rese >= 0.f) ? (sgb | (1u << b)) : (sgb & ~(1u << b));
            // patch nibble: static word loop, runtime predicate (registers only)
            const uint32_t sh = (uint32_t)(b & 7) * 4u;
#pragma unroll
            for (int w = 0; w < 4; ++w) {
                bool hit = (b >> 3) == w;
                uint32_t nw = (iw[w] & ~(0xFu << sh)) | ((uint32_t)qe << sh);
                iw[w] = hit ? nw : iw[w];
            }
        }

        // ---- residual scale (q-reduce: row m's 128 coords) + decode + z ----
        as += __shfl_xor(as, 16, 64);
        as += __shfl_xor(as, 32, 64);
        const float sc = as * (1.0f / 128.0f);
#pragma unroll
        for (int nt = 0; nt < 8; ++nt) {
            float zz[4];
#pragma unroll
            for (int qq = 0; qq < 4; ++qq) {
                const int b = nt * 4 + qq;
                const uint32_t nib = (iw[b >> 3] >> ((b & 7) * 4)) & 0xFu;
                const bool b0 = nib & 1u, b1 = nib & 2u, b2 = nib & 4u;
                float q01 = b0 ? cv[1] : cv[0];
                float q23 = b0 ? cv[3] : cv[2];
                float q45 = b0 ? cv[5] : cv[4];
                float q67 = b0 ? cv[7] : cv[6];
                float qA  = b1 ? q23 : q01;
                float qB  = b1 ? q67 : q45;
                float qf  = b2 ? qB : qA;
                zz[qq] = __fadd_rn(qf, ((sgb >> b) & 1u) ? sc : -sc);
            }
            uint2 pz = make_uint2(bf16rne(zz[0]) | (bf16rne(zz[1]) << 16),
                                  bf16rne(zz[2]) | (bf16rne(zz[3]) << 16));
            *reinterpret_cast<uint2*>(zout + rowoff + nt * 32 + q * 8) = pz;
        }
    }
}

// ===== Phase 2: out = (z @ Pi) * vn via bf16 MFMA — round-5 proven, verbatim =====
constexpr int BBLOCK = 256;
constexpr int BROWS  = 256;

__global__ __launch_bounds__(BBLOCK, 8)
void pq_phase2(const float* __restrict__ Pi, char* __restrict__ zio)
{
    __shared__ unsigned short piT[DIM * DIM];   // 32 KB

    const int tid  = threadIdx.x;
    const int wave = tid >> 6;
    const int lane = tid & 63;

#pragma unroll
    for (int s = 0; s < 4; ++s) {
        int sub = tid + s * BBLOCK;
        int a4 = (sub & 31) * 4;
        int b4 = (sub >> 5) * 4;
        float rv[4][4];
#pragma unroll
        for (int i = 0; i < 4; ++i)
            *reinterpret_cast<float4*>(rv[i]) =
                *reinterpret_cast<const float4*>(Pi + (size_t)(a4 + i) * DIM + b4);
#pragma unroll
        for (int j = 0; j < 4; ++j) {
            const int n   = b4 + j;
            const int ksw = a4 ^ ((n & 7) << 3);
            unsigned lo = bf16rne(rv[0][j]) | (bf16rne(rv[1][j]) << 16);
            unsigned hi = bf16rne(rv[2][j]) | (bf16rne(rv[3][j]) << 16);
            *reinterpret_cast<uint2*>(&piT[n * DIM + ksw]) = make_uint2(lo, hi);
        }
    }
    __syncthreads();

    const int rowbase0 = blockIdx.x * BROWS;

    for (int it = 0; it < BROWS / 64; ++it) {
        const int rowbase = rowbase0 + it * 64 + wave * 16;

        const char* zr = zio + (size_t)(rowbase + (lane & 15)) * ROW_BYTES + ((lane >> 4) * 16);
        short8 afr[4];
#pragma unroll
        for (int kf = 0; kf < 4; ++kf)
            afr[kf] = *reinterpret_cast<const short8*>(zr + kf * 64);

        float vnr[4];
#pragma unroll
        for (int qq = 0; qq < 4; ++qq)
            vnr[qq] = *reinterpret_cast<const float*>(
                zio + (size_t)(rowbase + (lane >> 4) * 4 + qq) * ROW_BYTES + 256);

#pragma unroll
        for (int nt = 0; nt < 8; ++nt) {
            const int n = nt * 16 + (lane & 15);
            f32x4 acc = {0.f, 0.f, 0.f, 0.f};
#pragma unroll
            for (int kf = 0; kf < 4; ++kf) {
                const int k0  = kf * 32 + (lane >> 4) * 8;
                const int ksw = k0 ^ ((n & 7) << 3);
                short8 bfr = *reinterpret_cast<const short8*>(&piT[n * DIM + ksw]);
                acc = __builtin_amdgcn_mfma_f32_16x16x32_bf16(afr[kf], bfr, acc, 0, 0, 0);
            }
#pragma unroll
            for (int qq = 0; qq < 4; ++qq) {
                float o = __fmul_rn(acc[qq], vnr[qq]);
                *reinterpret_cast<float*>(
                    zio + (size_t)(rowbase + (lane >> 4) * 4 + qq) * ROW_BYTES
                        + (size_t)(nt * 16 + (lane & 15)) * 4) = o;
            }
        }
    }
}

extern "C" void kernel_launch(void* const* d_in, const int* in_sizes, int n_in,
                              void* d_out, int out_size, void* d_ws, size_t ws_size,
                              hipStream_t stream) {
    const float* x   = (const float*)d_in[0];
    const float* Pi  = (const float*)d_in[1];
    const float* cen = (const float*)d_in[2];
    char* outp       = (char*)d_out;

    const int n_rows = in_sizes[0] / DIM;

    hipLaunchKernelGGL(k_rotquant, dim3(n_rows / P1_RPB), dim3(P1_BLOCK), 0, stream,
                       x, Pi, cen, outp);
    hipLaunchKernelGGL(pq_phase2, dim3(n_rows / BROWS), dim3(BBLOCK), 0, stream,
                       Pi, outp);
}